// Round 1
// baseline (793.248 us; speedup 1.0000x reference)
//
#include <hip/hip_runtime.h>

#define IN_DIM 128
#define OUT_DIM 128
#define NREL 3

// ---------- helpers ----------
__device__ __forceinline__ float bflo(unsigned u) { return __uint_as_float(u << 16); }
__device__ __forceinline__ float bfhi(unsigned u) { return __uint_as_float(u & 0xFFFF0000u); }
__device__ __forceinline__ unsigned f2bf(float f) {
  unsigned u = __float_as_uint(f);
  u = (u + 0x7FFFu + ((u >> 16) & 1u)) >> 16;
  return u;  // low 16 bits valid
}

// ---------- composed relation weights ----------
// Wkr[e][o=(h*16+j)][c] = sum_i Wk[s_e][h*16+i][c] * rel_att[e][h][i][j] * (pri[e][h]/4)
// Wvr analogous with rel_msg, no scale. Biases composed the same way.
__global__ void compose_w_kernel(const float* __restrict__ Wk, const float* __restrict__ bk,
                                 const float* __restrict__ Wv, const float* __restrict__ bv,
                                 const float* __restrict__ rel_att, const float* __restrict__ rel_msg,
                                 const float* __restrict__ rel_pri,
                                 float* __restrict__ Wkr, float* __restrict__ bkr,
                                 float* __restrict__ Wvr, float* __restrict__ bvr) {
  int e = blockIdx.x;   // relation
  int o = blockIdx.y;   // out index 0..127
  int z = blockIdx.z;   // 0 = att(k), 1 = msg(v)
  int c = threadIdx.x;  // in index 0..127
  int hd = o >> 4, j = o & 15;
  const int se[3] = {0, 1, 0};
  int s = se[e];
  const float* W = z ? Wv : Wk;
  const float* b = z ? bv : bk;
  const float* R = z ? rel_msg : rel_att;
  float scale = z ? 1.0f : (rel_pri[e * 8 + hd] * 0.25f);  // 1/sqrt(16)=0.25
  float acc = 0.0f, bacc = 0.0f;
#pragma unroll
  for (int i = 0; i < 16; ++i) {
    float r = R[((e * 8 + hd) * 16 + i) * 16 + j];
    acc += W[(s * 128 + hd * 16 + i) * 128 + c] * r;
    bacc += b[s * 128 + hd * 16 + i] * r;
  }
  float* Wo = z ? Wvr : Wkr;
  float* bo = z ? bvr : bkr;
  Wo[((size_t)e * 128 + o) * 128 + c] = acc * scale;
  if (c == 0) bo[e * 128 + o] = bacc * scale;
}

// ---------- projection GEMM: out_bf16 = A(fp32, Mx128) @ W^T(128x128) + b ----------
struct ProjJobs {
  const float* A[8];
  const float* W[8];
  const float* b[8];
  unsigned short* out[8];
  int M[8];
};

#define LS 129  // LDS row stride (floats)

__global__ __launch_bounds__(256) void proj_gemm_kernel(ProjJobs jobs) {
  __shared__ float As[128 * LS];
  __shared__ float Ws[128 * LS];
  int job = blockIdx.y;
  const float* __restrict__ A = jobs.A[job];
  const float* __restrict__ W = jobs.W[job];
  const float* __restrict__ bias = jobs.b[job];
  unsigned short* __restrict__ out = jobs.out[job];
  int M = jobs.M[job];
  int row0 = blockIdx.x * 128;
  if (row0 >= M) return;
  int t = threadIdx.x;
#pragma unroll
  for (int it = 0; it < 16; ++it) {
    int idx = it * 256 + t;    // 0..4095 float4 slots
    int m = idx >> 5;          // 0..127
    int k4 = (idx & 31) << 2;  // 0..124
    int row = row0 + m;
    float4 av = make_float4(0.f, 0.f, 0.f, 0.f);
    if (row < M) av = *(const float4*)(A + (size_t)row * 128 + k4);
    As[m * LS + k4 + 0] = av.x;
    As[m * LS + k4 + 1] = av.y;
    As[m * LS + k4 + 2] = av.z;
    As[m * LS + k4 + 3] = av.w;
    float4 wv = *(const float4*)(W + (size_t)idx * 4);
    Ws[m * LS + k4 + 0] = wv.x;
    Ws[m * LS + k4 + 1] = wv.y;
    Ws[m * LS + k4 + 2] = wv.z;
    Ws[m * LS + k4 + 3] = wv.w;
  }
  __syncthreads();
  int tr = t >> 4, tc = t & 15;
  int m0 = tr * 8, n0 = tc * 8;
  float acc[8][8];
#pragma unroll
  for (int i = 0; i < 8; ++i)
#pragma unroll
    for (int j = 0; j < 8; ++j) acc[i][j] = 0.f;
#pragma unroll 4
  for (int k = 0; k < 128; ++k) {
    float a[8], bb[8];
#pragma unroll
    for (int i = 0; i < 8; ++i) a[i] = As[(m0 + i) * LS + k];
#pragma unroll
    for (int j = 0; j < 8; ++j) bb[j] = Ws[(n0 + j) * LS + k];
#pragma unroll
    for (int i = 0; i < 8; ++i)
#pragma unroll
      for (int j = 0; j < 8; ++j) acc[i][j] += a[i] * bb[j];
  }
  float bv8[8];
#pragma unroll
  for (int j = 0; j < 8; ++j) bv8[j] = bias[n0 + j];
#pragma unroll
  for (int i = 0; i < 8; ++i) {
    int row = row0 + m0 + i;
    if (row < M) {
      unsigned sh[4];
#pragma unroll
      for (int j = 0; j < 4; ++j) {
        unsigned lo16 = f2bf(acc[i][2 * j] + bv8[2 * j]);
        unsigned hi16 = f2bf(acc[i][2 * j + 1] + bv8[2 * j + 1]);
        sh[j] = lo16 | (hi16 << 16);
      }
      uint4 u = make_uint4(sh[0], sh[1], sh[2], sh[3]);
      *(uint4*)(out + (size_t)row * 128 + n0) = u;
    }
  }
}

// ---------- final GEMM (in-place on d_out): out = a*(T@Wa^T+ba) + (1-a)*h ----------
__global__ __launch_bounds__(256) void final_gemm_kernel(
    float* __restrict__ dout, const float* __restrict__ Wa, const float* __restrict__ ba,
    const float* __restrict__ h0, const float* __restrict__ h1,
    const float* __restrict__ skip, int N0, int N1) {
  __shared__ float As[128 * LS];
  __shared__ float Ws[128 * LS];
  int type = blockIdx.y;
  int M = type ? N1 : N0;
  float* T = dout + (type ? (size_t)N0 * 128 : 0);
  const float* W = Wa + (size_t)type * 16384;
  const float* bias = ba + type * 128;
  const float* h = type ? h1 : h0;
  int row0 = blockIdx.x * 128;
  if (row0 >= M) return;
  int t = threadIdx.x;
#pragma unroll
  for (int it = 0; it < 16; ++it) {
    int idx = it * 256 + t;
    int m = idx >> 5;
    int k4 = (idx & 31) << 2;
    int row = row0 + m;
    float4 av = make_float4(0.f, 0.f, 0.f, 0.f);
    if (row < M) av = *(const float4*)(T + (size_t)row * 128 + k4);
    As[m * LS + k4 + 0] = av.x;
    As[m * LS + k4 + 1] = av.y;
    As[m * LS + k4 + 2] = av.z;
    As[m * LS + k4 + 3] = av.w;
    float4 wv = *(const float4*)(W + (size_t)idx * 4);
    Ws[m * LS + k4 + 0] = wv.x;
    Ws[m * LS + k4 + 1] = wv.y;
    Ws[m * LS + k4 + 2] = wv.z;
    Ws[m * LS + k4 + 3] = wv.w;
  }
  __syncthreads();
  int tr = t >> 4, tc = t & 15;
  int m0 = tr * 8, n0 = tc * 8;
  float acc[8][8];
#pragma unroll
  for (int i = 0; i < 8; ++i)
#pragma unroll
    for (int j = 0; j < 8; ++j) acc[i][j] = 0.f;
#pragma unroll 4
  for (int k = 0; k < 128; ++k) {
    float a[8], bb[8];
#pragma unroll
    for (int i = 0; i < 8; ++i) a[i] = As[(m0 + i) * LS + k];
#pragma unroll
    for (int j = 0; j < 8; ++j) bb[j] = Ws[(n0 + j) * LS + k];
#pragma unroll
    for (int i = 0; i < 8; ++i)
#pragma unroll
      for (int j = 0; j < 8; ++j) acc[i][j] += a[i] * bb[j];
  }
  float alpha = 1.0f / (1.0f + __expf(-skip[type]));
  float beta = 1.0f - alpha;
  float bv8[8];
#pragma unroll
  for (int j = 0; j < 8; ++j) bv8[j] = bias[n0 + j];
#pragma unroll
  for (int i = 0; i < 8; ++i) {
    int row = row0 + m0 + i;
    if (row < M) {
      float4 hv0 = *(const float4*)(h + (size_t)row * 128 + n0);
      float4 hv1 = *(const float4*)(h + (size_t)row * 128 + n0 + 4);
      float hv[8] = {hv0.x, hv0.y, hv0.z, hv0.w, hv1.x, hv1.y, hv1.z, hv1.w};
      float o[8];
#pragma unroll
      for (int j = 0; j < 8; ++j) o[j] = alpha * (acc[i][j] + bv8[j]) + beta * hv[j];
      float4 o0 = make_float4(o[0], o[1], o[2], o[3]);
      float4 o1 = make_float4(o[4], o[5], o[6], o[7]);
      *(float4*)(T + (size_t)row * 128 + n0) = o0;
      *(float4*)(T + (size_t)row * 128 + n0 + 4) = o1;
    }
  }
}

// ---------- CSR build ----------
__global__ void hist_kernel(const int* __restrict__ dst, int* __restrict__ cnt, int E) {
  int i = blockIdx.x * 256 + threadIdx.x;
  if (i < E) atomicAdd(&cnt[dst[i]], 1);
}

__global__ void scan1_kernel(const int* __restrict__ cnt, int* __restrict__ rp,
                             int* __restrict__ bsum, int n) {
  __shared__ int sd[256];
  int t = threadIdx.x;
  int base = blockIdx.x * 1024 + t * 4;
  int x[4];
#pragma unroll
  for (int j = 0; j < 4; ++j) x[j] = (base + j < n) ? cnt[base + j] : 0;
  int tsum = x[0] + x[1] + x[2] + x[3];
  sd[t] = tsum;
  __syncthreads();
  for (int off = 1; off < 256; off <<= 1) {
    int v = (t >= off) ? sd[t - off] : 0;
    __syncthreads();
    sd[t] += v;
    __syncthreads();
  }
  int run = sd[t] - tsum;  // exclusive
#pragma unroll
  for (int j = 0; j < 4; ++j) {
    if (base + j < n) rp[base + j] = run;
    run += x[j];
  }
  if (t == 255) bsum[blockIdx.x] = sd[255];
}

__global__ void scan2_kernel(int* __restrict__ bsum, int nb) {
  __shared__ int sd[256];
  int t = threadIdx.x;
  int v = (t < nb) ? bsum[t] : 0;
  sd[t] = v;
  __syncthreads();
  for (int off = 1; off < 256; off <<= 1) {
    int u = (t >= off) ? sd[t - off] : 0;
    __syncthreads();
    sd[t] += u;
    __syncthreads();
  }
  if (t < nb) bsum[t] = sd[t] - v;  // exclusive
}

__global__ void scan3_kernel(int* __restrict__ rp, const int* __restrict__ bsum, int n, int total) {
  int i = blockIdx.x * 256 + threadIdx.x;
  if (i < n) rp[i] += bsum[i >> 10];
  if (blockIdx.x == 0 && threadIdx.x == 0) rp[n] = total;
}

__global__ void scatter_kernel(const int* __restrict__ src, const int* __restrict__ dst,
                               const int* __restrict__ rp, int* __restrict__ cur,
                               int* __restrict__ ss, int E) {
  int i = blockIdx.x * 256 + threadIdx.x;
  if (i < E) {
    int d = dst[i];
    int pos = rp[d] + atomicAdd(&cur[d], 1);
    ss[pos] = src[i];
  }
}

// ---------- edge aggregation: one wave per dst node, single pass, no atomics ----------
// lane l owns elements (2l, 2l+1); head = l>>3; per-head dot via shfl_xor in 8-lane group.
__global__ __launch_bounds__(256) void agg_type0_kernel(
    const unsigned* __restrict__ qb,
    const unsigned* __restrict__ kr1, const unsigned* __restrict__ vr1,
    const int* __restrict__ rp1, const int* __restrict__ ss1,
    const unsigned* __restrict__ kr2, const unsigned* __restrict__ vr2,
    const int* __restrict__ rp2, const int* __restrict__ ss2,
    float* __restrict__ outT, int N) {
  int wid = (blockIdx.x * 256 + threadIdx.x) >> 6;
  int l = threadIdx.x & 63;
  if (wid >= N) return;
  unsigned q = qb[(size_t)wid * 64 + l];
  float qx = bflo(q), qy = bfhi(q);
  float rx = 0.f, ry = 0.f;
#pragma unroll
  for (int rel = 0; rel < 2; ++rel) {
    const unsigned* kr = rel ? kr2 : kr1;
    const unsigned* vr = rel ? vr2 : vr1;
    const int* rp = rel ? rp2 : rp1;
    const int* ss = rel ? ss2 : ss1;
    int beg = rp[wid], end = rp[wid + 1];
    float ax = 0.f, ay = 0.f, den = 0.f;
    for (int p = beg; p < end; ++p) {
      int s = ss[p];
      unsigned kb = kr[(size_t)s * 64 + l];
      float sc = qx * bflo(kb) + qy * bfhi(kb);
      sc += __shfl_xor(sc, 1);
      sc += __shfl_xor(sc, 2);
      sc += __shfl_xor(sc, 4);
      float e = __expf(sc);
      unsigned vb = vr[(size_t)s * 64 + l];
      den += e;
      ax += e * bflo(vb);
      ay += e * bfhi(vb);
    }
    if (end > beg) {
      float inv = 1.0f / den;
      rx += ax * inv;
      ry += ay * inv;
    }
  }
  rx *= 0.5f;  // mean over 2 relations
  ry *= 0.5f;
  *(float2*)(outT + (size_t)wid * 128 + 2 * l) = make_float2(rx, ry);
}

__global__ __launch_bounds__(256) void agg_type1_kernel(
    const unsigned* __restrict__ qb,
    const unsigned* __restrict__ kr0, const unsigned* __restrict__ vr0,
    const int* __restrict__ rp0, const int* __restrict__ ss0,
    float* __restrict__ outT, int N) {
  int wid = (blockIdx.x * 256 + threadIdx.x) >> 6;
  int l = threadIdx.x & 63;
  if (wid >= N) return;
  unsigned q = qb[(size_t)wid * 64 + l];
  float qx = bflo(q), qy = bfhi(q);
  float rx = 0.f, ry = 0.f;
  int beg = rp0[wid], end = rp0[wid + 1];
  float ax = 0.f, ay = 0.f, den = 0.f;
  for (int p = beg; p < end; ++p) {
    int s = ss0[p];
    unsigned kb = kr0[(size_t)s * 64 + l];
    float sc = qx * bflo(kb) + qy * bfhi(kb);
    sc += __shfl_xor(sc, 1);
    sc += __shfl_xor(sc, 2);
    sc += __shfl_xor(sc, 4);
    float e = __expf(sc);
    unsigned vb = vr0[(size_t)s * 64 + l];
    den += e;
    ax += e * bflo(vb);
    ay += e * bfhi(vb);
  }
  if (end > beg) {
    float inv = 1.0f / den;
    rx = ax * inv;
    ry = ay * inv;
  }
  *(float2*)(outT + (size_t)wid * 128 + 2 * l) = make_float2(rx, ry);
}

// ---------- host ----------
extern "C" void kernel_launch(void* const* d_in, const int* in_sizes, int n_in,
                              void* d_out, int out_size, void* d_ws, size_t ws_size,
                              hipStream_t stream) {
  const float* h0 = (const float*)d_in[0];
  const float* h1 = (const float*)d_in[1];
  const int* srcs[3] = {(const int*)d_in[2], (const int*)d_in[4], (const int*)d_in[6]};
  const int* dsts[3] = {(const int*)d_in[3], (const int*)d_in[5], (const int*)d_in[7]};
  const float* Wk = (const float*)d_in[8];
  const float* bk = (const float*)d_in[9];
  const float* Wq = (const float*)d_in[10];
  const float* bq = (const float*)d_in[11];
  const float* Wv = (const float*)d_in[12];
  const float* bv = (const float*)d_in[13];
  const float* Wa = (const float*)d_in[14];
  const float* ba = (const float*)d_in[15];
  const float* rel_att = (const float*)d_in[16];
  const float* rel_msg = (const float*)d_in[17];
  const float* rel_pri = (const float*)d_in[18];
  const float* skip = (const float*)d_in[19];

  int N0 = in_sizes[0] / 128;
  int N1 = in_sizes[1] / 128;
  int E = in_sizes[2];
  int nsrc[3] = {N0, N1, N0};
  int ndst[3] = {N1, N0, N0};
  int maxN = N0 > N1 ? N0 : N1;

  char* base = (char*)d_ws;
  size_t off = 0;
  auto alloc = [&](size_t bytes) -> void* {
    void* p = base + off;
    off += (bytes + 255) & ~(size_t)255;
    return p;
  };

  unsigned short* qb0 = (unsigned short*)alloc((size_t)N0 * 128 * 2);
  unsigned short* qb1 = (unsigned short*)alloc((size_t)N1 * 128 * 2);
  unsigned short* krb[3];
  unsigned short* vrb[3];
  for (int r = 0; r < 3; ++r) {
    krb[r] = (unsigned short*)alloc((size_t)nsrc[r] * 128 * 2);
    vrb[r] = (unsigned short*)alloc((size_t)nsrc[r] * 128 * 2);
  }
  float* Wkr = (float*)alloc((size_t)3 * 128 * 128 * 4);
  float* Wvr = (float*)alloc((size_t)3 * 128 * 128 * 4);
  float* bkr = (float*)alloc(3 * 128 * 4);
  float* bvr = (float*)alloc(3 * 128 * 4);
  int* rp[3];
  int* ss[3];
  for (int r = 0; r < 3; ++r) {
    rp[r] = (int*)alloc((size_t)(ndst[r] + 1) * 4);
    ss[r] = (int*)alloc((size_t)E * 4);
  }
  int* cnt = (int*)alloc((size_t)maxN * 4);
  int* bsum = (int*)alloc(256 * 4);
  (void)ws_size;

  // 1. composed weights
  compose_w_kernel<<<dim3(3, 128, 2), 128, 0, stream>>>(Wk, bk, Wv, bv, rel_att, rel_msg,
                                                        rel_pri, Wkr, bkr, Wvr, bvr);

  // 2. projection GEMMs -> bf16 q/kr/vr
  ProjJobs pj;
  const float* As_[8] = {h0, h1, h0, h1, h0, h0, h1, h0};
  const float* Ws_[8] = {Wq,        Wq + 16384, Wkr,         Wkr + 16384, Wkr + 32768,
                         Wvr,       Wvr + 16384, Wvr + 32768};
  const float* bs_[8] = {bq,        bq + 128,   bkr,         bkr + 128,   bkr + 256,
                         bvr,       bvr + 128,  bvr + 256};
  unsigned short* os_[8] = {qb0, qb1, krb[0], krb[1], krb[2], vrb[0], vrb[1], vrb[2]};
  int Ms_[8] = {N0, N1, N0, N1, N0, N0, N1, N0};
  for (int j = 0; j < 8; ++j) {
    pj.A[j] = As_[j];
    pj.W[j] = Ws_[j];
    pj.b[j] = bs_[j];
    pj.out[j] = os_[j];
    pj.M[j] = Ms_[j];
  }
  proj_gemm_kernel<<<dim3((maxN + 127) / 128, 8), 256, 0, stream>>>(pj);

  // 3. CSR per relation
  for (int r = 0; r < 3; ++r) {
    int n = ndst[r];
    hipMemsetAsync(cnt, 0, (size_t)n * 4, stream);
    hist_kernel<<<(E + 255) / 256, 256, 0, stream>>>(dsts[r], cnt, E);
    int nb = (n + 1023) / 1024;
    scan1_kernel<<<nb, 256, 0, stream>>>(cnt, rp[r], bsum, n);
    scan2_kernel<<<1, 256, 0, stream>>>(bsum, nb);
    scan3_kernel<<<(n + 255) / 256, 256, 0, stream>>>(rp[r], bsum, n, E);
    hipMemsetAsync(cnt, 0, (size_t)n * 4, stream);
    scatter_kernel<<<(E + 255) / 256, 256, 0, stream>>>(srcs[r], dsts[r], rp[r], cnt, ss[r], E);
  }

  // 4. edge aggregation -> t-means written into d_out
  float* t0 = (float*)d_out;                      // N0 rows
  float* t1 = (float*)d_out + (size_t)N0 * 128;   // N1 rows
  agg_type0_kernel<<<(N0 + 3) / 4, 256, 0, stream>>>(
      (const unsigned*)qb0, (const unsigned*)krb[1], (const unsigned*)vrb[1], rp[1], ss[1],
      (const unsigned*)krb[2], (const unsigned*)vrb[2], rp[2], ss[2], t0, N0);
  agg_type1_kernel<<<(N1 + 3) / 4, 256, 0, stream>>>(
      (const unsigned*)qb1, (const unsigned*)krb[0], (const unsigned*)vrb[0], rp[0], ss[0], t1, N1);

  // 5. final GEMM + skip blend, in-place on d_out
  final_gemm_kernel<<<dim3((maxN + 127) / 128, 2), 256, 0, stream>>>(
      (float*)d_out, Wa, ba, h0, h1, skip, N0, N1);
}

// Round 2
// 491.558 us; speedup vs baseline: 1.6137x; 1.6137x over previous
//
#include <hip/hip_runtime.h>

typedef __attribute__((ext_vector_type(8))) short bf16x8;
typedef __attribute__((ext_vector_type(4))) float f32x4;

// ---------- helpers ----------
__device__ __forceinline__ float bflo(unsigned u) { return __uint_as_float(u << 16); }
__device__ __forceinline__ float bfhi(unsigned u) { return __uint_as_float(u & 0xFFFF0000u); }
__device__ __forceinline__ unsigned f2bf(float f) {
  unsigned u = __float_as_uint(f);
  u = (u + 0x7FFFu + ((u >> 16) & 1u)) >> 16;
  return u;  // low 16 bits valid
}

// ---------- fp32 -> bf16 bulk convert (n multiple of 8) ----------
__global__ void cvt_bf16_kernel(const float* __restrict__ in, unsigned short* __restrict__ out,
                                int n8) {
  int i = blockIdx.x * 256 + threadIdx.x;
  if (i >= n8) return;
  const float4* p = (const float4*)(in + (size_t)i * 8);
  float4 x = p[0], y = p[1];
  uint4 v;
  v.x = f2bf(x.x) | (f2bf(x.y) << 16);
  v.y = f2bf(x.z) | (f2bf(x.w) << 16);
  v.z = f2bf(y.x) | (f2bf(y.y) << 16);
  v.w = f2bf(y.z) | (f2bf(y.w) << 16);
  *(uint4*)(out + (size_t)i * 8) = v;
}

// ---------- composed relation weights (bf16 out, fp32 bias) ----------
// Wkr[e][o=(h*16+j)][c] = sum_i Wk[s_e][h*16+i][c] * rel_att[e][h][i][j] * (pri[e][h]/4)
__global__ void compose_w_kernel(const float* __restrict__ Wk, const float* __restrict__ bk,
                                 const float* __restrict__ Wv, const float* __restrict__ bv,
                                 const float* __restrict__ rel_att, const float* __restrict__ rel_msg,
                                 const float* __restrict__ rel_pri,
                                 unsigned short* __restrict__ Wkr, float* __restrict__ bkr,
                                 unsigned short* __restrict__ Wvr, float* __restrict__ bvr) {
  int e = blockIdx.x;   // relation
  int o = blockIdx.y;   // out index 0..127
  int z = blockIdx.z;   // 0 = att(k), 1 = msg(v)
  int c = threadIdx.x;  // in index 0..127
  int hd = o >> 4, j = o & 15;
  const int se[3] = {0, 1, 0};
  int s = se[e];
  const float* W = z ? Wv : Wk;
  const float* b = z ? bv : bk;
  const float* R = z ? rel_msg : rel_att;
  float scale = z ? 1.0f : (rel_pri[e * 8 + hd] * 0.25f);  // 1/sqrt(16)=0.25
  float acc = 0.0f, bacc = 0.0f;
#pragma unroll
  for (int i = 0; i < 16; ++i) {
    float r = R[((e * 8 + hd) * 16 + i) * 16 + j];
    acc += W[(s * 128 + hd * 16 + i) * 128 + c] * r;
    bacc += b[s * 128 + hd * 16 + i] * r;
  }
  unsigned short* Wo = z ? Wvr : Wkr;
  float* bo = z ? bvr : bkr;
  Wo[((size_t)e * 128 + o) * 128 + c] = (unsigned short)f2bf(acc * scale);
  if (c == 0) bo[e * 128 + o] = bacc * scale;
}

// ---------- MFMA projection GEMM: out_bf16 = bf16(A_fp32) @ Wb^T + bias ----------
struct ProjJobs {
  const float* A[8];          // fp32 Mx128
  const unsigned short* W[8]; // bf16 128x128, [out][in]
  const float* b[8];          // fp32 bias
  unsigned short* out[8];     // bf16 Mx128
  int M[8];
};

__global__ __launch_bounds__(256) void proj_gemm_mfma(ProjJobs jobs) {
  __shared__ short As[128 * 128];
  __shared__ short Bs[128 * 128];
  int job = blockIdx.y;
  const float* __restrict__ A = jobs.A[job];
  const unsigned short* __restrict__ W = jobs.W[job];
  const float* __restrict__ bias = jobs.b[job];
  unsigned short* __restrict__ out = jobs.out[job];
  int M = jobs.M[job];
  int row0 = blockIdx.x * 128;
  if (row0 >= M) return;
  int t = threadIdx.x;
  bool full = (row0 + 128 <= M);
#pragma unroll
  for (int it = 0; it < 8; ++it) {
    int o = (it * 256 + t) * 8;  // element index in 128x128 tile
    int row = o >> 7, col = o & 127;
    int gr = row0 + row;
    uint4 av = make_uint4(0, 0, 0, 0);
    if (full || gr < M) {
      float4 x = *(const float4*)(A + (size_t)gr * 128 + col);
      float4 y = *(const float4*)(A + (size_t)gr * 128 + col + 4);
      av.x = f2bf(x.x) | (f2bf(x.y) << 16);
      av.y = f2bf(x.z) | (f2bf(x.w) << 16);
      av.z = f2bf(y.x) | (f2bf(y.y) << 16);
      av.w = f2bf(y.z) | (f2bf(y.w) << 16);
    }
    int sw = o ^ ((row & 7) << 3);  // XOR swizzle (short-index bits 3..5)
    *(uint4*)(&As[sw]) = av;
    uint4 wv = *(const uint4*)(W + o);
    *(uint4*)(&Bs[sw]) = wv;
  }
  __syncthreads();
  int wid = t >> 6, l = t & 63;
  int wr = wid >> 1, wc = wid & 1;  // 2x2 waves, 64x64 each
  int lr = l & 15, kb = l >> 4;
  f32x4 acc[4][4] = {};
#pragma unroll
  for (int ks = 0; ks < 4; ++ks) {
    bf16x8 af[4], bfr[4];
#pragma unroll
    for (int m = 0; m < 4; ++m) {
      int row = wr * 64 + m * 16 + lr;
      int h = (row * 128 + kb * 8 + ks * 32) ^ ((row & 7) << 3);
      af[m] = *(bf16x8*)(&As[h]);
    }
#pragma unroll
    for (int n = 0; n < 4; ++n) {
      int row = wc * 64 + n * 16 + lr;
      int h = (row * 128 + kb * 8 + ks * 32) ^ ((row & 7) << 3);
      bfr[n] = *(bf16x8*)(&Bs[h]);
    }
#pragma unroll
    for (int m = 0; m < 4; ++m)
#pragma unroll
      for (int n = 0; n < 4; ++n)
        acc[m][n] = __builtin_amdgcn_mfma_f32_16x16x32_bf16(af[m], bfr[n], acc[m][n], 0, 0, 0);
  }
  // epilogue: C/D layout col=lane&15, row=(lane>>4)*4+reg
  int rb = row0 + wr * 64 + (l >> 4) * 4;
#pragma unroll
  for (int m = 0; m < 4; ++m)
#pragma unroll
    for (int j = 0; j < 4; ++j) {
      int grow = rb + m * 16 + j;
      if (grow < M) {
#pragma unroll
        for (int n = 0; n < 4; ++n) {
          int col = wc * 64 + n * 16 + lr;
          out[(size_t)grow * 128 + col] = (unsigned short)f2bf(acc[m][n][j] + bias[col]);
        }
      }
    }
}

// ---------- MFMA final GEMM: d_out = a*(Tb@Wa^T+ba) + (1-a)*h ----------
__global__ __launch_bounds__(256) void final_gemm_mfma(
    float* __restrict__ dout, const unsigned short* __restrict__ Tb0,
    const unsigned short* __restrict__ Tb1, const unsigned short* __restrict__ Wab,
    const float* __restrict__ ba, const float* __restrict__ h0, const float* __restrict__ h1,
    const float* __restrict__ skip, int N0, int N1) {
  __shared__ short As[128 * 128];
  __shared__ short Bs[128 * 128];
  int type = blockIdx.y;
  int M = type ? N1 : N0;
  const unsigned short* T = type ? Tb1 : Tb0;
  const unsigned short* W = Wab + (size_t)type * 16384;
  const float* bias = ba + type * 128;
  const float* h = type ? h1 : h0;
  float* O = dout + (type ? (size_t)N0 * 128 : 0);
  int row0 = blockIdx.x * 128;
  if (row0 >= M) return;
  int t = threadIdx.x;
  bool full = (row0 + 128 <= M);
#pragma unroll
  for (int it = 0; it < 8; ++it) {
    int o = (it * 256 + t) * 8;
    int row = o >> 7;
    int gr = row0 + row;
    uint4 av = make_uint4(0, 0, 0, 0);
    if (full || gr < M) av = *(const uint4*)(T + (size_t)gr * 128 + (o & 127));
    int sw = o ^ ((row & 7) << 3);
    *(uint4*)(&As[sw]) = av;
    uint4 wv = *(const uint4*)(W + o);
    *(uint4*)(&Bs[sw]) = wv;
  }
  __syncthreads();
  int wid = t >> 6, l = t & 63;
  int wr = wid >> 1, wc = wid & 1;
  int lr = l & 15, kb = l >> 4;
  f32x4 acc[4][4] = {};
#pragma unroll
  for (int ks = 0; ks < 4; ++ks) {
    bf16x8 af[4], bfr[4];
#pragma unroll
    for (int m = 0; m < 4; ++m) {
      int row = wr * 64 + m * 16 + lr;
      int h2 = (row * 128 + kb * 8 + ks * 32) ^ ((row & 7) << 3);
      af[m] = *(bf16x8*)(&As[h2]);
    }
#pragma unroll
    for (int n = 0; n < 4; ++n) {
      int row = wc * 64 + n * 16 + lr;
      int h2 = (row * 128 + kb * 8 + ks * 32) ^ ((row & 7) << 3);
      bfr[n] = *(bf16x8*)(&Bs[h2]);
    }
#pragma unroll
    for (int m = 0; m < 4; ++m)
#pragma unroll
      for (int n = 0; n < 4; ++n)
        acc[m][n] = __builtin_amdgcn_mfma_f32_16x16x32_bf16(af[m], bfr[n], acc[m][n], 0, 0, 0);
  }
  float alpha = 1.0f / (1.0f + __expf(-skip[type]));
  float beta = 1.0f - alpha;
  int rb = row0 + wr * 64 + (l >> 4) * 4;
#pragma unroll
  for (int m = 0; m < 4; ++m)
#pragma unroll
    for (int j = 0; j < 4; ++j) {
      int grow = rb + m * 16 + j;
      if (grow < M) {
#pragma unroll
        for (int n = 0; n < 4; ++n) {
          int col = wc * 64 + n * 16 + lr;
          float vout = alpha * (acc[m][n][j] + bias[col]) + beta * h[(size_t)grow * 128 + col];
          O[(size_t)grow * 128 + col] = vout;
        }
      }
    }
}

// ---------- CSR build ----------
__global__ void hist_kernel(const int* __restrict__ dst, int* __restrict__ cnt, int E) {
  int i = blockIdx.x * 256 + threadIdx.x;
  if (i < E) atomicAdd(&cnt[dst[i]], 1);
}

__global__ void scan1_kernel(const int* __restrict__ cnt, int* __restrict__ rp,
                             int* __restrict__ bsum, int n) {
  __shared__ int sd[256];
  int t = threadIdx.x;
  int base = blockIdx.x * 1024 + t * 4;
  int x[4];
#pragma unroll
  for (int j = 0; j < 4; ++j) x[j] = (base + j < n) ? cnt[base + j] : 0;
  int tsum = x[0] + x[1] + x[2] + x[3];
  sd[t] = tsum;
  __syncthreads();
  for (int off = 1; off < 256; off <<= 1) {
    int v = (t >= off) ? sd[t - off] : 0;
    __syncthreads();
    sd[t] += v;
    __syncthreads();
  }
  int run = sd[t] - tsum;  // exclusive
#pragma unroll
  for (int j = 0; j < 4; ++j) {
    if (base + j < n) rp[base + j] = run;
    run += x[j];
  }
  if (t == 255) bsum[blockIdx.x] = sd[255];
}

__global__ void scan2_kernel(int* __restrict__ bsum, int nb) {
  __shared__ int sd[256];
  int t = threadIdx.x;
  int v = (t < nb) ? bsum[t] : 0;
  sd[t] = v;
  __syncthreads();
  for (int off = 1; off < 256; off <<= 1) {
    int u = (t >= off) ? sd[t - off] : 0;
    __syncthreads();
    sd[t] += u;
    __syncthreads();
  }
  if (t < nb) bsum[t] = sd[t] - v;  // exclusive
}

__global__ void scan3_kernel(int* __restrict__ rp, const int* __restrict__ bsum, int n, int total) {
  int i = blockIdx.x * 256 + threadIdx.x;
  if (i < n) rp[i] += bsum[i >> 10];
  if (blockIdx.x == 0 && threadIdx.x == 0) rp[n] = total;
}

__global__ void scatter_kernel(const int* __restrict__ src, const int* __restrict__ dst,
                               const int* __restrict__ rp, int* __restrict__ cur,
                               int* __restrict__ ss, int E) {
  int i = blockIdx.x * 256 + threadIdx.x;
  if (i < E) {
    int d = dst[i];
    int pos = rp[d] + atomicAdd(&cur[d], 1);
    ss[pos] = src[i];
  }
}

// ---------- edge aggregation: one wave per dst node, no atomics, bf16 out ----------
__global__ __launch_bounds__(256) void agg_type0_kernel(
    const unsigned* __restrict__ qb,
    const unsigned* __restrict__ kr1, const unsigned* __restrict__ vr1,
    const int* __restrict__ rp1, const int* __restrict__ ss1,
    const unsigned* __restrict__ kr2, const unsigned* __restrict__ vr2,
    const int* __restrict__ rp2, const int* __restrict__ ss2,
    unsigned* __restrict__ Tb, int N) {
  int wid = (blockIdx.x * 256 + threadIdx.x) >> 6;
  int l = threadIdx.x & 63;
  if (wid >= N) return;
  unsigned q = qb[(size_t)wid * 64 + l];
  float qx = bflo(q), qy = bfhi(q);
  float rx = 0.f, ry = 0.f;
#pragma unroll
  for (int rel = 0; rel < 2; ++rel) {
    const unsigned* kr = rel ? kr2 : kr1;
    const unsigned* vr = rel ? vr2 : vr1;
    const int* rp = rel ? rp2 : rp1;
    const int* ss = rel ? ss2 : ss1;
    int beg = rp[wid], end = rp[wid + 1];
    float ax = 0.f, ay = 0.f, den = 0.f;
    for (int p = beg; p < end; ++p) {
      int s = ss[p];
      unsigned kb = kr[(size_t)s * 64 + l];
      float sc = qx * bflo(kb) + qy * bfhi(kb);
      sc += __shfl_xor(sc, 1);
      sc += __shfl_xor(sc, 2);
      sc += __shfl_xor(sc, 4);
      float e = __expf(sc);
      unsigned vb = vr[(size_t)s * 64 + l];
      den += e;
      ax += e * bflo(vb);
      ay += e * bfhi(vb);
    }
    if (end > beg) {
      float inv = 1.0f / den;
      rx += ax * inv;
      ry += ay * inv;
    }
  }
  rx *= 0.5f;
  ry *= 0.5f;
  Tb[(size_t)wid * 64 + l] = f2bf(rx) | (f2bf(ry) << 16);
}

__global__ __launch_bounds__(256) void agg_type1_kernel(
    const unsigned* __restrict__ qb,
    const unsigned* __restrict__ kr0, const unsigned* __restrict__ vr0,
    const int* __restrict__ rp0, const int* __restrict__ ss0,
    unsigned* __restrict__ Tb, int N) {
  int wid = (blockIdx.x * 256 + threadIdx.x) >> 6;
  int l = threadIdx.x & 63;
  if (wid >= N) return;
  unsigned q = qb[(size_t)wid * 64 + l];
  float qx = bflo(q), qy = bfhi(q);
  float rx = 0.f, ry = 0.f;
  int beg = rp0[wid], end = rp0[wid + 1];
  float ax = 0.f, ay = 0.f, den = 0.f;
  for (int p = beg; p < end; ++p) {
    int s = ss0[p];
    unsigned kb = kr0[(size_t)s * 64 + l];
    float sc = qx * bflo(kb) + qy * bfhi(kb);
    sc += __shfl_xor(sc, 1);
    sc += __shfl_xor(sc, 2);
    sc += __shfl_xor(sc, 4);
    float e = __expf(sc);
    unsigned vb = vr0[(size_t)s * 64 + l];
    den += e;
    ax += e * bflo(vb);
    ay += e * bfhi(vb);
  }
  if (end > beg) {
    float inv = 1.0f / den;
    rx = ax * inv;
    ry = ay * inv;
  }
  Tb[(size_t)wid * 64 + l] = f2bf(rx) | (f2bf(ry) << 16);
}

// ---------- host ----------
extern "C" void kernel_launch(void* const* d_in, const int* in_sizes, int n_in,
                              void* d_out, int out_size, void* d_ws, size_t ws_size,
                              hipStream_t stream) {
  const float* h0 = (const float*)d_in[0];
  const float* h1 = (const float*)d_in[1];
  const int* srcs[3] = {(const int*)d_in[2], (const int*)d_in[4], (const int*)d_in[6]};
  const int* dsts[3] = {(const int*)d_in[3], (const int*)d_in[5], (const int*)d_in[7]};
  const float* Wk = (const float*)d_in[8];
  const float* bk = (const float*)d_in[9];
  const float* Wq = (const float*)d_in[10];
  const float* bq = (const float*)d_in[11];
  const float* Wv = (const float*)d_in[12];
  const float* bv = (const float*)d_in[13];
  const float* Wa = (const float*)d_in[14];
  const float* ba = (const float*)d_in[15];
  const float* rel_att = (const float*)d_in[16];
  const float* rel_msg = (const float*)d_in[17];
  const float* rel_pri = (const float*)d_in[18];
  const float* skip = (const float*)d_in[19];

  int N0 = in_sizes[0] / 128;
  int N1 = in_sizes[1] / 128;
  int E = in_sizes[2];
  int nsrc[3] = {N0, N1, N0};
  int ndst[3] = {N1, N0, N0};
  int maxN = N0 > N1 ? N0 : N1;

  char* base = (char*)d_ws;
  size_t off = 0;
  auto alloc = [&](size_t bytes) -> void* {
    void* p = base + off;
    off += (bytes + 255) & ~(size_t)255;
    return p;
  };

  unsigned short* qb0 = (unsigned short*)alloc((size_t)N0 * 128 * 2);
  unsigned short* qb1 = (unsigned short*)alloc((size_t)N1 * 128 * 2);
  unsigned short* krb[3];
  unsigned short* vrb[3];
  for (int r = 0; r < 3; ++r) {
    krb[r] = (unsigned short*)alloc((size_t)nsrc[r] * 128 * 2);
    vrb[r] = (unsigned short*)alloc((size_t)nsrc[r] * 128 * 2);
  }
  unsigned short* Tb0 = (unsigned short*)alloc((size_t)N0 * 128 * 2);
  unsigned short* Tb1 = (unsigned short*)alloc((size_t)N1 * 128 * 2);
  unsigned short* Wkrb = (unsigned short*)alloc((size_t)3 * 16384 * 2);
  unsigned short* Wvrb = (unsigned short*)alloc((size_t)3 * 16384 * 2);
  unsigned short* Wqb = (unsigned short*)alloc((size_t)2 * 16384 * 2);
  unsigned short* Wab = (unsigned short*)alloc((size_t)2 * 16384 * 2);
  float* bkr = (float*)alloc(3 * 128 * 4);
  float* bvr = (float*)alloc(3 * 128 * 4);
  int* rp[3];
  int* ss[3];
  for (int r = 0; r < 3; ++r) {
    rp[r] = (int*)alloc((size_t)(ndst[r] + 1) * 4);
    ss[r] = (int*)alloc((size_t)E * 4);
  }
  int* cnt = (int*)alloc((size_t)maxN * 4);
  int* bsum = (int*)alloc(256 * 4);
  (void)ws_size;

  // 1. weight prep
  compose_w_kernel<<<dim3(3, 128, 2), 128, 0, stream>>>(Wk, bk, Wv, bv, rel_att, rel_msg,
                                                        rel_pri, Wkrb, bkr, Wvrb, bvr);
  cvt_bf16_kernel<<<16, 256, 0, stream>>>(Wq, Wqb, 4096);
  cvt_bf16_kernel<<<16, 256, 0, stream>>>(Wa, Wab, 4096);

  // 2. projection GEMMs -> bf16 q/kr/vr (fp32->bf16 fused in staging)
  ProjJobs pj;
  const float* As_[8] = {h0, h1, h0, h1, h0, h0, h1, h0};
  const unsigned short* Ws_[8] = {Wqb,  Wqb + 16384,  Wkrb,        Wkrb + 16384, Wkrb + 32768,
                                  Wvrb, Wvrb + 16384, Wvrb + 32768};
  const float* bs_[8] = {bq, bq + 128, bkr, bkr + 128, bkr + 256, bvr, bvr + 128, bvr + 256};
  unsigned short* os_[8] = {qb0, qb1, krb[0], krb[1], krb[2], vrb[0], vrb[1], vrb[2]};
  int Ms_[8] = {N0, N1, N0, N1, N0, N0, N1, N0};
  for (int j = 0; j < 8; ++j) {
    pj.A[j] = As_[j];
    pj.W[j] = Ws_[j];
    pj.b[j] = bs_[j];
    pj.out[j] = os_[j];
    pj.M[j] = Ms_[j];
  }
  proj_gemm_mfma<<<dim3((maxN + 127) / 128, 8), 256, 0, stream>>>(pj);

  // 3. CSR per relation
  for (int r = 0; r < 3; ++r) {
    int n = ndst[r];
    hipMemsetAsync(cnt, 0, (size_t)n * 4, stream);
    hist_kernel<<<(E + 255) / 256, 256, 0, stream>>>(dsts[r], cnt, E);
    int nb = (n + 1023) / 1024;
    scan1_kernel<<<nb, 256, 0, stream>>>(cnt, rp[r], bsum, n);
    scan2_kernel<<<1, 256, 0, stream>>>(bsum, nb);
    scan3_kernel<<<(n + 255) / 256, 256, 0, stream>>>(rp[r], bsum, n, E);
    hipMemsetAsync(cnt, 0, (size_t)n * 4, stream);
    scatter_kernel<<<(E + 255) / 256, 256, 0, stream>>>(srcs[r], dsts[r], rp[r], cnt, ss[r], E);
  }

  // 4. edge aggregation -> bf16 T
  agg_type0_kernel<<<(N0 + 3) / 4, 256, 0, stream>>>(
      (const unsigned*)qb0, (const unsigned*)krb[1], (const unsigned*)vrb[1], rp[1], ss[1],
      (const unsigned*)krb[2], (const unsigned*)vrb[2], rp[2], ss[2], (unsigned*)Tb0, N0);
  agg_type1_kernel<<<(N1 + 3) / 4, 256, 0, stream>>>(
      (const unsigned*)qb1, (const unsigned*)krb[0], (const unsigned*)vrb[0], rp[0], ss[0],
      (unsigned*)Tb1, N1);

  // 5. final GEMM + skip blend -> fp32 d_out
  final_gemm_mfma<<<dim3((maxN + 127) / 128, 2), 256, 0, stream>>>(
      (float*)d_out, Tb0, Tb1, Wab, ba, h0, h1, skip, N0, N1);
}

// Round 3
// 334.061 us; speedup vs baseline: 2.3746x; 1.4715x over previous
//
#include <hip/hip_runtime.h>

typedef __attribute__((ext_vector_type(8))) short bf16x8;
typedef __attribute__((ext_vector_type(4))) float f32x4;

// ---------- helpers ----------
__device__ __forceinline__ float bflo(unsigned u) { return __uint_as_float(u << 16); }
__device__ __forceinline__ float bfhi(unsigned u) { return __uint_as_float(u & 0xFFFF0000u); }
__device__ __forceinline__ unsigned f2bf(float f) {
  unsigned u = __float_as_uint(f);
  u = (u + 0x7FFFu + ((u >> 16) & 1u)) >> 16;
  return u;  // low 16 bits valid
}

// DPP-based add from lane (l ^ mask) within 16-lane row. VALU-speed (no LDS).
#define DPPADD(v, ctrl) \
  ((v) + __int_as_float(__builtin_amdgcn_update_dpp(0, __float_as_int(v), ctrl, 0xF, 0xF, true)))

// ---------- fp32 -> bf16 bulk convert (n multiple of 8) ----------
__global__ void cvt_bf16_kernel(const float* __restrict__ in, unsigned short* __restrict__ out,
                                int n8) {
  int i = blockIdx.x * 256 + threadIdx.x;
  if (i >= n8) return;
  const float4* p = (const float4*)(in + (size_t)i * 8);
  float4 x = p[0], y = p[1];
  uint4 v;
  v.x = f2bf(x.x) | (f2bf(x.y) << 16);
  v.y = f2bf(x.z) | (f2bf(x.w) << 16);
  v.z = f2bf(y.x) | (f2bf(y.y) << 16);
  v.w = f2bf(y.z) | (f2bf(y.w) << 16);
  *(uint4*)(out + (size_t)i * 8) = v;
}

// ---------- composed relation weights (bf16 out, fp32 bias) ----------
__global__ void compose_w_kernel(const float* __restrict__ Wk, const float* __restrict__ bk,
                                 const float* __restrict__ Wv, const float* __restrict__ bv,
                                 const float* __restrict__ rel_att, const float* __restrict__ rel_msg,
                                 const float* __restrict__ rel_pri,
                                 unsigned short* __restrict__ Wkr, float* __restrict__ bkr,
                                 unsigned short* __restrict__ Wvr, float* __restrict__ bvr) {
  int e = blockIdx.x;   // relation
  int o = blockIdx.y;   // out index 0..127
  int z = blockIdx.z;   // 0 = att(k), 1 = msg(v)
  int c = threadIdx.x;  // in index 0..127
  int hd = o >> 4, j = o & 15;
  const int se[3] = {0, 1, 0};
  int s = se[e];
  const float* W = z ? Wv : Wk;
  const float* b = z ? bv : bk;
  const float* R = z ? rel_msg : rel_att;
  float scale = z ? 1.0f : (rel_pri[e * 8 + hd] * 0.25f);  // 1/sqrt(16)=0.25
  float acc = 0.0f, bacc = 0.0f;
#pragma unroll
  for (int i = 0; i < 16; ++i) {
    float r = R[((e * 8 + hd) * 16 + i) * 16 + j];
    acc += W[(s * 128 + hd * 16 + i) * 128 + c] * r;
    bacc += b[s * 128 + hd * 16 + i] * r;
  }
  unsigned short* Wo = z ? Wvr : Wkr;
  float* bo = z ? bvr : bkr;
  Wo[((size_t)e * 128 + o) * 128 + c] = (unsigned short)f2bf(acc * scale);
  if (c == 0) bo[e * 128 + o] = bacc * scale;
}

// ---------- fused MFMA projection GEMM: A staged once, loop over weight mats ----------
struct ProjFP {
  const float* A[2];  // h0, h1 fp32
  int M[2];
  int nj[2];                     // 5, 3
  const unsigned short* W[10];   // [type*5 + j]
  const float* b[10];
  unsigned short* out[10];
  int ostr[10];                  // row stride in shorts
};

__global__ __launch_bounds__(256) void proj_gemm_fused(ProjFP P) {
  __shared__ short As[128 * 128];
  __shared__ short Bs[128 * 128];
  int type = blockIdx.y;
  const float* __restrict__ A = P.A[type];
  int M = P.M[type];
  int nj = P.nj[type];
  int base = type * 5;
  int row0 = blockIdx.x * 128;
  if (row0 >= M) return;
  int t = threadIdx.x;
  bool full = (row0 + 128 <= M);
  // stage A (fp32 -> bf16) once
#pragma unroll
  for (int it = 0; it < 8; ++it) {
    int o = (it * 256 + t) * 8;
    int row = o >> 7, col = o & 127;
    int gr = row0 + row;
    uint4 av = make_uint4(0, 0, 0, 0);
    if (full || gr < M) {
      float4 x = *(const float4*)(A + (size_t)gr * 128 + col);
      float4 y = *(const float4*)(A + (size_t)gr * 128 + col + 4);
      av.x = f2bf(x.x) | (f2bf(x.y) << 16);
      av.y = f2bf(x.z) | (f2bf(x.w) << 16);
      av.z = f2bf(y.x) | (f2bf(y.y) << 16);
      av.w = f2bf(y.z) | (f2bf(y.w) << 16);
    }
    int sw = o ^ ((row & 7) << 3);
    *(uint4*)(&As[sw]) = av;
  }
  // stage B for job 0
  {
    const unsigned short* W0 = P.W[base];
#pragma unroll
    for (int it = 0; it < 8; ++it) {
      int o = (it * 256 + t) * 8;
      int row = o >> 7;
      int sw = o ^ ((row & 7) << 3);
      *(uint4*)(&Bs[sw]) = *(const uint4*)(W0 + o);
    }
  }
  __syncthreads();
  int wid = t >> 6, l = t & 63;
  int wr = wid >> 1, wc = wid & 1;  // 2x2 waves, 64x64 each
  int lr = l & 15, kb = l >> 4;
  for (int j = 0;; ++j) {
    f32x4 acc[4][4] = {};
#pragma unroll
    for (int ks = 0; ks < 4; ++ks) {
      bf16x8 af[4], bfr[4];
#pragma unroll
      for (int m = 0; m < 4; ++m) {
        int row = wr * 64 + m * 16 + lr;
        int h = (row * 128 + kb * 8 + ks * 32) ^ ((row & 7) << 3);
        af[m] = *(bf16x8*)(&As[h]);
      }
#pragma unroll
      for (int n = 0; n < 4; ++n) {
        int row = wc * 64 + n * 16 + lr;
        int h = (row * 128 + kb * 8 + ks * 32) ^ ((row & 7) << 3);
        bfr[n] = *(bf16x8*)(&Bs[h]);
      }
#pragma unroll
      for (int m = 0; m < 4; ++m)
#pragma unroll
        for (int n = 0; n < 4; ++n)
          acc[m][n] = __builtin_amdgcn_mfma_f32_16x16x32_bf16(af[m], bfr[n], acc[m][n], 0, 0, 0);
    }
    // epilogue for job j
    const float* bias = P.b[base + j];
    unsigned short* out = P.out[base + j];
    int ostr = P.ostr[base + j];
    int rb = row0 + wr * 64 + (l >> 4) * 4;
#pragma unroll
    for (int m = 0; m < 4; ++m)
#pragma unroll
      for (int jr = 0; jr < 4; ++jr) {
        int grow = rb + m * 16 + jr;
        if (grow < M) {
#pragma unroll
          for (int n = 0; n < 4; ++n) {
            int col = wc * 64 + n * 16 + lr;
            out[(size_t)grow * ostr + col] = (unsigned short)f2bf(acc[m][n][jr] + bias[col]);
          }
        }
      }
    if (j + 1 >= nj) break;
    __syncthreads();
    {
      const unsigned short* Wj = P.W[base + j + 1];
#pragma unroll
      for (int it = 0; it < 8; ++it) {
        int o = (it * 256 + t) * 8;
        int row = o >> 7;
        int sw = o ^ ((row & 7) << 3);
        *(uint4*)(&Bs[sw]) = *(const uint4*)(Wj + o);
      }
    }
    __syncthreads();
  }
}

// ---------- MFMA final GEMM: d_out = a*(Tb@Wa^T+ba) + (1-a)*h ----------
__global__ __launch_bounds__(256) void final_gemm_mfma(
    float* __restrict__ dout, const unsigned short* __restrict__ Tb0,
    const unsigned short* __restrict__ Tb1, const unsigned short* __restrict__ Wab,
    const float* __restrict__ ba, const float* __restrict__ h0, const float* __restrict__ h1,
    const float* __restrict__ skip, int N0, int N1) {
  __shared__ short As[128 * 128];
  __shared__ short Bs[128 * 128];
  int type = blockIdx.y;
  int M = type ? N1 : N0;
  const unsigned short* T = type ? Tb1 : Tb0;
  const unsigned short* W = Wab + (size_t)type * 16384;
  const float* bias = ba + type * 128;
  const float* h = type ? h1 : h0;
  float* O = dout + (type ? (size_t)N0 * 128 : 0);
  int row0 = blockIdx.x * 128;
  if (row0 >= M) return;
  int t = threadIdx.x;
  bool full = (row0 + 128 <= M);
#pragma unroll
  for (int it = 0; it < 8; ++it) {
    int o = (it * 256 + t) * 8;
    int row = o >> 7;
    int gr = row0 + row;
    uint4 av = make_uint4(0, 0, 0, 0);
    if (full || gr < M) av = *(const uint4*)(T + (size_t)gr * 128 + (o & 127));
    int sw = o ^ ((row & 7) << 3);
    *(uint4*)(&As[sw]) = av;
    uint4 wv = *(const uint4*)(W + o);
    *(uint4*)(&Bs[sw]) = wv;
  }
  __syncthreads();
  int wid = t >> 6, l = t & 63;
  int wr = wid >> 1, wc = wid & 1;
  int lr = l & 15, kb = l >> 4;
  f32x4 acc[4][4] = {};
#pragma unroll
  for (int ks = 0; ks < 4; ++ks) {
    bf16x8 af[4], bfr[4];
#pragma unroll
    for (int m = 0; m < 4; ++m) {
      int row = wr * 64 + m * 16 + lr;
      int h2 = (row * 128 + kb * 8 + ks * 32) ^ ((row & 7) << 3);
      af[m] = *(bf16x8*)(&As[h2]);
    }
#pragma unroll
    for (int n = 0; n < 4; ++n) {
      int row = wc * 64 + n * 16 + lr;
      int h2 = (row * 128 + kb * 8 + ks * 32) ^ ((row & 7) << 3);
      bfr[n] = *(bf16x8*)(&Bs[h2]);
    }
#pragma unroll
    for (int m = 0; m < 4; ++m)
#pragma unroll
      for (int n = 0; n < 4; ++n)
        acc[m][n] = __builtin_amdgcn_mfma_f32_16x16x32_bf16(af[m], bfr[n], acc[m][n], 0, 0, 0);
  }
  float alpha = 1.0f / (1.0f + __expf(-skip[type]));
  float beta = 1.0f - alpha;
  int rb = row0 + wr * 64 + (l >> 4) * 4;
#pragma unroll
  for (int m = 0; m < 4; ++m)
#pragma unroll
    for (int jr = 0; jr < 4; ++jr) {
      int grow = rb + m * 16 + jr;
      if (grow < M) {
#pragma unroll
        for (int n = 0; n < 4; ++n) {
          int col = wc * 64 + n * 16 + lr;
          float vout = alpha * (acc[m][n][jr] + bias[col]) + beta * h[(size_t)grow * 128 + col];
          O[(size_t)grow * 128 + col] = vout;
        }
      }
    }
}

// ---------- CSR build (batched over 3 relations via gridDim.y) ----------
__global__ void hist3_kernel(const int* __restrict__ d0, const int* __restrict__ d1,
                             const int* __restrict__ d2, int* __restrict__ cnt, int maxN, int E) {
  int r = blockIdx.y;
  int i = blockIdx.x * 256 + threadIdx.x;
  const int* dst = r == 0 ? d0 : (r == 1 ? d1 : d2);
  if (i < E) atomicAdd(&cnt[(size_t)r * maxN + dst[i]], 1);
}

__global__ void scan1_kernel(const int* __restrict__ cnt, int* __restrict__ rp0,
                             int* __restrict__ rp1, int* __restrict__ rp2,
                             int* __restrict__ bsum, int maxN, int n0, int n1, int n2) {
  __shared__ int sd[256];
  int r = blockIdx.y;
  int n = r == 0 ? n0 : (r == 1 ? n1 : n2);
  int* rp = r == 0 ? rp0 : (r == 1 ? rp1 : rp2);
  const int* c = cnt + (size_t)r * maxN;
  int t = threadIdx.x;
  int base = blockIdx.x * 1024 + t * 4;
  int x[4];
#pragma unroll
  for (int j = 0; j < 4; ++j) x[j] = (base + j < n) ? c[base + j] : 0;
  int tsum = x[0] + x[1] + x[2] + x[3];
  sd[t] = tsum;
  __syncthreads();
  for (int off = 1; off < 256; off <<= 1) {
    int v = (t >= off) ? sd[t - off] : 0;
    __syncthreads();
    sd[t] += v;
    __syncthreads();
  }
  int run = sd[t] - tsum;  // exclusive
#pragma unroll
  for (int j = 0; j < 4; ++j) {
    if (base + j < n) rp[base + j] = run;
    run += x[j];
  }
  if (t == 255) bsum[r * 256 + blockIdx.x] = sd[255];
}

__global__ void scan2_kernel(int* __restrict__ bsum, int nb) {
  __shared__ int sd[256];
  int r = blockIdx.y;
  int* bs = bsum + r * 256;
  int t = threadIdx.x;
  int v = (t < nb) ? bs[t] : 0;
  sd[t] = v;
  __syncthreads();
  for (int off = 1; off < 256; off <<= 1) {
    int u = (t >= off) ? sd[t - off] : 0;
    __syncthreads();
    sd[t] += u;
    __syncthreads();
  }
  if (t < nb) bs[t] = sd[t] - v;  // exclusive
}

__global__ void scan3_kernel(int* __restrict__ rp0, int* __restrict__ rp1, int* __restrict__ rp2,
                             const int* __restrict__ bsum, int n0, int n1, int n2, int total) {
  int r = blockIdx.y;
  int n = r == 0 ? n0 : (r == 1 ? n1 : n2);
  int* rp = r == 0 ? rp0 : (r == 1 ? rp1 : rp2);
  int i = blockIdx.x * 256 + threadIdx.x;
  if (i < n) rp[i] += bsum[r * 256 + (i >> 10)];
  if (blockIdx.x == 0 && threadIdx.x == 0) rp[n] = total;
}

__global__ void scatter3_kernel(const int* __restrict__ s0, const int* __restrict__ d0,
                                const int* __restrict__ s1, const int* __restrict__ d1,
                                const int* __restrict__ s2, const int* __restrict__ d2,
                                const int* __restrict__ rp0, const int* __restrict__ rp1,
                                const int* __restrict__ rp2, int* __restrict__ cur, int maxN,
                                int* __restrict__ ss0, int* __restrict__ ss1,
                                int* __restrict__ ss2, int E) {
  int r = blockIdx.y;
  int i = blockIdx.x * 256 + threadIdx.x;
  if (i >= E) return;
  const int* src = r == 0 ? s0 : (r == 1 ? s1 : s2);
  const int* dst = r == 0 ? d0 : (r == 1 ? d1 : d2);
  const int* rp = r == 0 ? rp0 : (r == 1 ? rp1 : rp2);
  int* ss = r == 0 ? ss0 : (r == 1 ? ss1 : ss2);
  int d = dst[i];
  int pos = rp[d] + atomicAdd(&cur[(size_t)r * maxN + d], 1);
  ss[pos] = src[i];
}

// ---------- edge aggregation: one wave per dst node, DPP reduce, 4-edge batches ----------
struct AggP {
  const unsigned *qb0, *qb1, *kv0, *kv1, *kv2;
  const int *rp0, *ss0, *rp1, *ss1, *rp2, *ss2;
  unsigned *Tb0, *Tb1;
  int N0, N1;
};

__device__ __forceinline__ void accum_rel(const unsigned* __restrict__ kv,
                                          const int* __restrict__ rp, const int* __restrict__ ss,
                                          int node, int l, float qx, float qy,
                                          float& rx, float& ry) {
  int beg = __builtin_amdgcn_readfirstlane(rp[node]);
  int end = __builtin_amdgcn_readfirstlane(rp[node + 1]);
  if (end <= beg) return;
  float ax = 0.f, ay = 0.f, den = 0.f;
  for (int p = beg; p < end; p += 4) {
    int p1 = (p + 1 < end) ? p + 1 : p;
    int p2 = (p + 2 < end) ? p + 2 : p;
    int p3 = (p + 3 < end) ? p + 3 : p;
    float m1 = (p + 1 < end) ? 1.f : 0.f;
    float m2 = (p + 2 < end) ? 1.f : 0.f;
    float m3 = (p + 3 < end) ? 1.f : 0.f;
    int s0 = __builtin_amdgcn_readfirstlane(ss[p]);
    int s1 = __builtin_amdgcn_readfirstlane(ss[p1]);
    int s2 = __builtin_amdgcn_readfirstlane(ss[p2]);
    int s3 = __builtin_amdgcn_readfirstlane(ss[p3]);
    const unsigned* r0 = kv + (size_t)s0 * 128;
    const unsigned* r1 = kv + (size_t)s1 * 128;
    const unsigned* r2 = kv + (size_t)s2 * 128;
    const unsigned* r3 = kv + (size_t)s3 * 128;
    unsigned kb0 = r0[l], kb1 = r1[l], kb2 = r2[l], kb3 = r3[l];
    unsigned vb0 = r0[64 + l], vb1 = r1[64 + l], vb2 = r2[64 + l], vb3 = r3[64 + l];
    float sc0 = qx * bflo(kb0) + qy * bfhi(kb0);
    float sc1 = qx * bflo(kb1) + qy * bfhi(kb1);
    float sc2 = qx * bflo(kb2) + qy * bfhi(kb2);
    float sc3 = qx * bflo(kb3) + qy * bfhi(kb3);
    // 8-lane head reduce: xor1, xor2 (quad_perm), xor7 (row_half_mirror == cross-quad)
    sc0 = DPPADD(sc0, 0xB1); sc0 = DPPADD(sc0, 0x4E); sc0 = DPPADD(sc0, 0x141);
    sc1 = DPPADD(sc1, 0xB1); sc1 = DPPADD(sc1, 0x4E); sc1 = DPPADD(sc1, 0x141);
    sc2 = DPPADD(sc2, 0xB1); sc2 = DPPADD(sc2, 0x4E); sc2 = DPPADD(sc2, 0x141);
    sc3 = DPPADD(sc3, 0xB1); sc3 = DPPADD(sc3, 0x4E); sc3 = DPPADD(sc3, 0x141);
    float e0 = __expf(sc0);
    float e1 = __expf(sc1) * m1;
    float e2 = __expf(sc2) * m2;
    float e3 = __expf(sc3) * m3;
    den += (e0 + e1) + (e2 + e3);
    ax += e0 * bflo(vb0) + e1 * bflo(vb1) + e2 * bflo(vb2) + e3 * bflo(vb3);
    ay += e0 * bfhi(vb0) + e1 * bfhi(vb1) + e2 * bfhi(vb2) + e3 * bfhi(vb3);
  }
  float inv = 1.0f / den;
  rx += ax * inv;
  ry += ay * inv;
}

__global__ __launch_bounds__(256) void agg_all_kernel(AggP P) {
  int gw = (blockIdx.x * 256 + threadIdx.x) >> 6;
  int l = threadIdx.x & 63;
  if (gw < P.N0) {
    unsigned q = P.qb0[(size_t)gw * 64 + l];
    float qx = bflo(q), qy = bfhi(q);
    float rx = 0.f, ry = 0.f;
    accum_rel(P.kv1, P.rp1, P.ss1, gw, l, qx, qy, rx, ry);
    accum_rel(P.kv2, P.rp2, P.ss2, gw, l, qx, qy, rx, ry);
    P.Tb0[(size_t)gw * 64 + l] = f2bf(rx * 0.5f) | (f2bf(ry * 0.5f) << 16);
  } else if (gw < P.N0 + P.N1) {
    int n = gw - P.N0;
    unsigned q = P.qb1[(size_t)n * 64 + l];
    float qx = bflo(q), qy = bfhi(q);
    float rx = 0.f, ry = 0.f;
    accum_rel(P.kv0, P.rp0, P.ss0, n, l, qx, qy, rx, ry);
    P.Tb1[(size_t)n * 64 + l] = f2bf(rx) | (f2bf(ry) << 16);
  }
}

// ---------- host ----------
extern "C" void kernel_launch(void* const* d_in, const int* in_sizes, int n_in,
                              void* d_out, int out_size, void* d_ws, size_t ws_size,
                              hipStream_t stream) {
  const float* h0 = (const float*)d_in[0];
  const float* h1 = (const float*)d_in[1];
  const int* srcs[3] = {(const int*)d_in[2], (const int*)d_in[4], (const int*)d_in[6]};
  const int* dsts[3] = {(const int*)d_in[3], (const int*)d_in[5], (const int*)d_in[7]};
  const float* Wk = (const float*)d_in[8];
  const float* bk = (const float*)d_in[9];
  const float* Wq = (const float*)d_in[10];
  const float* bq = (const float*)d_in[11];
  const float* Wv = (const float*)d_in[12];
  const float* bv = (const float*)d_in[13];
  const float* Wa = (const float*)d_in[14];
  const float* ba = (const float*)d_in[15];
  const float* rel_att = (const float*)d_in[16];
  const float* rel_msg = (const float*)d_in[17];
  const float* rel_pri = (const float*)d_in[18];
  const float* skip = (const float*)d_in[19];

  int N0 = in_sizes[0] / 128;
  int N1 = in_sizes[1] / 128;
  int E = in_sizes[2];
  int nsrc[3] = {N0, N1, N0};
  int ndst[3] = {N1, N0, N0};
  int maxN = N0 > N1 ? N0 : N1;

  char* base = (char*)d_ws;
  size_t off = 0;
  auto alloc = [&](size_t bytes) -> void* {
    void* p = base + off;
    off += (bytes + 255) & ~(size_t)255;
    return p;
  };

  unsigned short* qb0 = (unsigned short*)alloc((size_t)N0 * 128 * 2);
  unsigned short* qb1 = (unsigned short*)alloc((size_t)N1 * 128 * 2);
  unsigned short* kvb[3];  // interleaved [N][kr(128) | vr(128)] bf16
  for (int r = 0; r < 3; ++r) kvb[r] = (unsigned short*)alloc((size_t)nsrc[r] * 256 * 2);
  unsigned short* Tb0 = (unsigned short*)alloc((size_t)N0 * 128 * 2);
  unsigned short* Tb1 = (unsigned short*)alloc((size_t)N1 * 128 * 2);
  unsigned short* Wkrb = (unsigned short*)alloc((size_t)3 * 16384 * 2);
  unsigned short* Wvrb = (unsigned short*)alloc((size_t)3 * 16384 * 2);
  unsigned short* Wqb = (unsigned short*)alloc((size_t)2 * 16384 * 2);
  unsigned short* Wab = (unsigned short*)alloc((size_t)2 * 16384 * 2);
  float* bkr = (float*)alloc(3 * 128 * 4);
  float* bvr = (float*)alloc(3 * 128 * 4);
  int* rp[3];
  int* ss[3];
  for (int r = 0; r < 3; ++r) {
    rp[r] = (int*)alloc((size_t)(ndst[r] + 1) * 4);
    ss[r] = (int*)alloc((size_t)(E + 8) * 4);
  }
  int* cnt6 = (int*)alloc((size_t)6 * maxN * 4);  // cnt (hist) + cur (scatter)
  int* bsum = (int*)alloc(3 * 256 * 4);
  (void)ws_size;

  // 1. weight prep
  compose_w_kernel<<<dim3(3, 128, 2), 128, 0, stream>>>(Wk, bk, Wv, bv, rel_att, rel_msg,
                                                        rel_pri, Wkrb, bkr, Wvrb, bvr);
  cvt_bf16_kernel<<<16, 256, 0, stream>>>(Wq, Wqb, 4096);
  cvt_bf16_kernel<<<16, 256, 0, stream>>>(Wa, Wab, 4096);

  // 2. fused projection GEMMs -> bf16 q + interleaved kv tables
  ProjFP pf;
  pf.A[0] = h0; pf.A[1] = h1;
  pf.M[0] = N0; pf.M[1] = N1;
  pf.nj[0] = 5; pf.nj[1] = 3;
  // type0 jobs: q, kr(rel0), kr(rel2), vr(rel0), vr(rel2)
  pf.W[0] = Wqb;            pf.b[0] = bq;        pf.out[0] = qb0;          pf.ostr[0] = 128;
  pf.W[1] = Wkrb;           pf.b[1] = bkr;       pf.out[1] = kvb[0];       pf.ostr[1] = 256;
  pf.W[2] = Wkrb + 32768;   pf.b[2] = bkr + 256; pf.out[2] = kvb[2];       pf.ostr[2] = 256;
  pf.W[3] = Wvrb;           pf.b[3] = bvr;       pf.out[3] = kvb[0] + 128; pf.ostr[3] = 256;
  pf.W[4] = Wvrb + 32768;   pf.b[4] = bvr + 256; pf.out[4] = kvb[2] + 128; pf.ostr[4] = 256;
  // type1 jobs: q, kr(rel1), vr(rel1)
  pf.W[5] = Wqb + 16384;    pf.b[5] = bq + 128;  pf.out[5] = qb1;          pf.ostr[5] = 128;
  pf.W[6] = Wkrb + 16384;   pf.b[6] = bkr + 128; pf.out[6] = kvb[1];       pf.ostr[6] = 256;
  pf.W[7] = Wvrb + 16384;   pf.b[7] = bvr + 128; pf.out[7] = kvb[1] + 128; pf.ostr[7] = 256;
  pf.W[8] = Wqb; pf.b[8] = bq; pf.out[8] = qb0; pf.ostr[8] = 128;  // unused
  pf.W[9] = Wqb; pf.b[9] = bq; pf.out[9] = qb0; pf.ostr[9] = 128;  // unused
  proj_gemm_fused<<<dim3((maxN + 127) / 128, 2), 256, 0, stream>>>(pf);

  // 3. CSR per relation (batched, gridDim.y = 3)
  hipMemsetAsync(cnt6, 0, (size_t)6 * maxN * 4, stream);
  hist3_kernel<<<dim3((E + 255) / 256, 3), 256, 0, stream>>>(dsts[0], dsts[1], dsts[2], cnt6,
                                                             maxN, E);
  int nb = (maxN + 1023) / 1024;
  scan1_kernel<<<dim3(nb, 3), 256, 0, stream>>>(cnt6, rp[0], rp[1], rp[2], bsum, maxN,
                                                ndst[0], ndst[1], ndst[2]);
  scan2_kernel<<<dim3(1, 3), 256, 0, stream>>>(bsum, nb);
  scan3_kernel<<<dim3((maxN + 255) / 256, 3), 256, 0, stream>>>(rp[0], rp[1], rp[2], bsum,
                                                                ndst[0], ndst[1], ndst[2], E);
  scatter3_kernel<<<dim3((E + 255) / 256, 3), 256, 0, stream>>>(
      srcs[0], dsts[0], srcs[1], dsts[1], srcs[2], dsts[2], rp[0], rp[1], rp[2],
      cnt6 + (size_t)3 * maxN, maxN, ss[0], ss[1], ss[2], E);

  // 4. edge aggregation -> bf16 T (one kernel, both types)
  AggP ap;
  ap.qb0 = (const unsigned*)qb0; ap.qb1 = (const unsigned*)qb1;
  ap.kv0 = (const unsigned*)kvb[0]; ap.kv1 = (const unsigned*)kvb[1];
  ap.kv2 = (const unsigned*)kvb[2];
  ap.rp0 = rp[0]; ap.ss0 = ss[0];
  ap.rp1 = rp[1]; ap.ss1 = ss[1];
  ap.rp2 = rp[2]; ap.ss2 = ss[2];
  ap.Tb0 = (unsigned*)Tb0; ap.Tb1 = (unsigned*)Tb1;
  ap.N0 = N0; ap.N1 = N1;
  int totw = N0 + N1;
  agg_all_kernel<<<(totw + 3) / 4, 256, 0, stream>>>(ap);

  // 5. final GEMM + skip blend -> fp32 d_out
  final_gemm_mfma<<<dim3((maxN + 127) / 128, 2), 256, 0, stream>>>(
      (float*)d_out, Tb0, Tb1, Wab, ba, h0, h1, skip, N0, N1);
}